// Round 2
// baseline (348.757 us; speedup 1.0000x reference)
//
#include <hip/hip_runtime.h>
#include <stdint.h>

#define HW 9216
#define CDIM 128
#define WIDTH 96
#define BATCH 2
#define SPLITS 4            // 4 key-splits x 2 wk-waves = 8 partial streams
#define KSPLIT 2304         // keys per split
#define NTILE 36            // 2304 / 64 keys per LDS tile
#define QTILE 128           // q-rows per block
#define NQT (HW / QTILE)    // 72 q-tiles
#define NWG (NQT * SPLITS * BATCH)   // 576 blocks -> all co-resident @3/CU

// Logits: w = dot * QSCALE, e = (e^w)^2 = exp(dot/(0.1*sqrt(128))).
// |dot|<=1 -> |w|<=0.442: packed Taylor-4 + square, rel err ~3e-4 (<< f16 noise).
#define QSCALE 0.44194173824159216f
// conf numerator: exp(2*mx) = exp2(mx * 2/ln2)
#define MXSCALE 2.8853900817779268f

typedef _Float16 half8 __attribute__((ext_vector_type(8)));
typedef float f32x16 __attribute__((ext_vector_type(16)));
typedef float float2v __attribute__((ext_vector_type(2)));

// ---------------------------------------------------------------------------
// Kernel 1: L2-normalize over C, write fp16 [B][HW][C] (unchanged).
// ---------------------------------------------------------------------------
__global__ __launch_bounds__(256) void norm_kernel(const float* __restrict__ fL,
                                                   const float* __restrict__ fR,
                                                   _Float16* __restrict__ Qh,
                                                   _Float16* __restrict__ Kh)
{
    __shared__ float ssred[4][64];
    __shared__ _Float16 ot[64 * 130];   // +2 halves pad -> bank advance 1/row

    const float* src = (blockIdx.y == 0) ? fL : fR;
    _Float16* dst    = (blockIdx.y == 0) ? Qh : Kh;
    const float outScale = (blockIdx.y == 0) ? QSCALE : 1.0f;

    const int t = threadIdx.x;
    const int pos_l = t & 63, cg = t >> 6;            // 4 channel groups of 32
    const int pos0 = blockIdx.x * 64;                  // 64 | HW so no straddle
    const int b = pos0 / HW, pos_in = pos0 % HW + pos_l;

    const float* p = src + (size_t)b * CDIM * HW + pos_in;

    float v[32];
    float ss = 0.f;
    #pragma unroll
    for (int j = 0; j < 32; ++j) {
        v[j] = p[(size_t)(cg * 32 + j) * HW];
        ss += v[j] * v[j];
    }
    ssred[cg][pos_l] = ss;
    __syncthreads();
    float tot = ssred[0][pos_l] + ssred[1][pos_l] + ssred[2][pos_l] + ssred[3][pos_l];
    float scale = outScale / fmaxf(sqrtf(tot), 1e-6f);

    #pragma unroll
    for (int j = 0; j < 32; ++j)
        ot[pos_l * 130 + cg * 32 + j] = (_Float16)(v[j] * scale);
    __syncthreads();

    uint4* og = (uint4*)(dst + (size_t)(b * HW + pos0 % HW + 0) * CDIM);
    #pragma unroll
    for (int i = 0; i < 4; ++i) {
        int idx = i * 256 + t;            // 0..1023 dwordx4 slots
        int row = idx >> 4, chunk = idx & 15;
        og[idx] = *(const uint4*)&ot[row * 130 + chunk * 8];
    }
}

// ---------------------------------------------------------------------------
// Kernel 2: fused correlation + softmax-accumulate, counted-vmcnt pipeline.
//   Block: 512 thr = 8 waves as 4(wq) x 2(wk) over 128q x 64k tiles.
//   LDS: 3 x 16 KB buffers (48 KB -> 3 blocks/CU, 24 waves), prefetch depth 2.
//   Per tile: sched_barrier(0); s_waitcnt vmcnt(2) (own tile-t loads landed,
//   tile t+1 stays IN FLIGHT -- never drained to 0); raw s_barrier;
//   issue STAGE(t+2); ds_read frags; 8 MFMA; poly-exp epilogue.
//   Reuse safety: buf[(t+2)%3] was consumed at iter t-1; every wave's iter
//   t-1 ds_reads complete before its MFMAs (compiler lgkmcnt), which the
//   sched_barrier(0) pins before the iter-t wait -> before barrier_t ->
//   before any wave's STAGE(t+2) DMA issues. vmcnt(2) before the barrier
//   makes each wave's tile-t DMA visible in LDS to all waves after it.
//   XCD-chunked remap: 576 = 8 x 72 -> each XCD owns one (split,b): K-split
//   (576 KB) + Q slice (2.36 MB) L2-resident.
// ---------------------------------------------------------------------------
__global__ __launch_bounds__(512, 6) void attn_kernel(const _Float16* __restrict__ Qh,
                                                      const _Float16* __restrict__ Kh,
                                                      float4* __restrict__ part)
{
    __shared__ __align__(16) _Float16 Ks[3 * 64 * 128];   // 3 x 16 KB

    // bijective XCD swizzle (NWG % 8 == 0): xcd = wg & 7 gets chunk [72*xcd, ...)
    const int wg0 = blockIdx.x;
    const int nid = (wg0 & 7) * (NWG / 8) + (wg0 >> 3);
    const int qt = nid % NQT;
    const int split = (nid / NQT) % SPLITS;
    const int b = nid / (NQT * SPLITS);

    const int t = threadIdx.x;
    const int lane = t & 63, wave = t >> 6;        // 8 waves
    const int wq = wave >> 1, wk = wave & 1;       // 4 (q) x 2 (k)
    const int lane31 = lane & 31, hi = lane >> 5;
    const int ln15 = lane & 15, qd = lane >> 4;

    const char* kp0 = (const char*)(Kh + (size_t)b * HW * CDIM) +
                      (size_t)(split * KSPLIT) * (CDIM * 2);

    // ---- Q fragments (B-operand): col = lane31 = q-row, k = hi*8+j ----
    // issued FIRST so the loop's vmcnt(2) leaves only tile-1 DMA outstanding
    half8 qf[8];
    {
        const char* qb = (const char*)(Qh +
            ((size_t)(b * HW + qt * QTILE + wq * 32 + lane31)) * CDIM);
        #pragma unroll
        for (int kc = 0; kc < 8; ++kc)
            qf[kc] = *(const half8*)(qb + kc * 32 + hi * 16);
    }

    // staging: wave stages rows [wave*8, wave*8+8) of the 64-row tile.
    // LDS dest linear (instr adds lane*16B); source 16B-chunk XOR-swizzled so
    // LDS[r][c] = K[r][c ^ (r&15)] -> conflict-free fragment reads.
    int voff[2];
    #pragma unroll
    for (int i = 0; i < 2; ++i) {
        int r = wave * 8 + i * 4 + qd;
        voff[i] = r * 256 + ((ln15 ^ (r & 15)) << 4);
    }

    #define STAGE(TILE, BUF)                                                     \
        {                                                                        \
            const char* kb_ = kp0 + (size_t)(TILE) * 16384;                      \
            _Float16* db_ = &Ks[(BUF) * 8192 + wave * (8 * 128)];                \
            _Pragma("unroll")                                                    \
            for (int i_ = 0; i_ < 2; ++i_)                                       \
                __builtin_amdgcn_global_load_lds(                                \
                    (const __attribute__((address_space(1))) uint32_t*)(kb_ + voff[i_]), \
                    (__attribute__((address_space(3))) uint32_t*)(db_ + i_ * (4 * 128)), \
                    16, 0, 0);                                                   \
        }

    STAGE(0, 0);
    STAGE(1, 1);

    // K-frag (A-operand) LDS byte offsets: row = wk*32 + lane31, chunk
    // (kc*2+hi) un-swizzled via ^ln15 (row&15 == ln15).
    int rdoff[8];
    #pragma unroll
    for (int kc = 0; kc < 8; ++kc)
        rdoff[kc] = ((wk * 32 + lane31) << 8) + ((((kc << 1) | hi) ^ ln15) << 4);

    // period-3 coordinate tables:
    // key = split*2304 + kt*64 + wk*32 + crow + 4hi;
    // x = 32*((2kt+wk)%3) + crow + 4hi (never wraps: base<=64, off<=31)
    // y = split*24 + (2kt+wk)/3 + 2*(kt/3)   (tile-constant)
    float xb[3], yw[3];
    #pragma unroll
    for (int p = 0; p < 3; ++p) {
        xb[p] = (float)(32 * ((2 * p + wk) % 3));
        yw[p] = (float)(split * 24 + (2 * p + wk) / 3);
    }

    float2v E2[8];                       // per reg-pair e-sums (crow applied at end)
    #pragma unroll
    for (int p = 0; p < 8; ++p) E2[p] = (float2v)0.f;
    float2v mx2 = (float2v)(-1.0e30f);
    float2v axb2 = (float2v)0.f, ay2 = (float2v)0.f;

    const char* ksb = (const char*)&Ks[0];
    const float2v C4 = (float2v)(1.0f / 24.0f), C3 = (float2v)(1.0f / 6.0f),
                  C2 = (float2v)0.5f, C1 = (float2v)1.0f;

    #pragma unroll
    for (int kt = 0; kt < NTILE; ++kt) {
        const int cur = kt % 3;                    // buffer (== coord phase)
        const float yadd = (float)(2 * (kt / 3));  // compile-time literal

        // rule #18: pin prior iteration's MFMA/epilogue (register-only ops
        // can otherwise sink past asm memory barriers) above the wait.
        __builtin_amdgcn_sched_barrier(0);
        if (kt < NTILE - 1) asm volatile("s_waitcnt vmcnt(2)" ::: "memory");
        else                asm volatile("s_waitcnt vmcnt(0)" ::: "memory");
        __builtin_amdgcn_s_barrier();
        __builtin_amdgcn_sched_barrier(0);
        if (kt < NTILE - 2) STAGE(kt + 2, (kt + 2) % 3);

        f32x16 acc;
        __builtin_amdgcn_s_setprio(1);
        #pragma unroll
        for (int kc = 0; kc < 8; ++kc) {
            half8 kf = *(const half8*)(ksb + cur * 16384 + rdoff[kc]);
            acc = __builtin_amdgcn_mfma_f32_32x32x16_f16(
                kf, qf[kc], (kc == 0) ? (f32x16)0.f : acc, 0, 0, 0);
        }
        __builtin_amdgcn_s_setprio(0);

        // ---- epilogue: packed poly-exp + slot accumulate ----
        float2v lt2;
        #pragma unroll
        for (int p = 0; p < 8; ++p) {
            float2v w;
            w.x = acc[2 * p];
            w.y = acc[2 * p + 1];
            mx2 = __builtin_elementwise_max(mx2, w);
            float2v h = w * C4 + C3;          // e^w, Taylor-4 on |w|<=0.442
            h = h * w + C2;
            h = h * w + C1;
            h = h * w + C1;
            float2v e = h * h;                // square back to full range
            E2[p] += e;
            lt2 = (p == 0) ? e : (lt2 + e);
        }
        axb2 += lt2 * (float2v)xb[cur];
        ay2  += lt2 * (float2v)(yw[cur] + yadd);
    }

    // ---- per-lane fold: apply compile-time crow weights once ----
    float l = 0.f, axc = 0.f;
    #pragma unroll
    for (int p = 0; p < 8; ++p) {
        const float c0 = (float)(((2 * p) & 3) + 8 * ((2 * p) >> 2)); // 0,2,8,...,26
        l   += E2[p].x + E2[p].y;
        axc += c0 * E2[p].x + (c0 + 1.0f) * E2[p].y;
    }
    float ax = axc + (float)(4 * hi) * l + axb2.x + axb2.y;
    float ay = ay2.x + ay2.y;
    float mx = fmaxf(mx2.x, mx2.y);

    // combine hi/lo key-halves (lanes l and l+32 share q = lane31)
    l  += __shfl_xor(l, 32, 64);
    ax += __shfl_xor(ax, 32, 64);
    ay += __shfl_xor(ay, 32, 64);
    mx  = fmaxf(mx, __shfl_xor(mx, 32, 64));

    if (hi == 0) {
        int row = qt * QTILE + wq * 32 + lane31;
        part[(size_t)(split * 2 + wk) * (BATCH * HW) + b * HW + row] =
            make_float4(l, ax, ay, __builtin_amdgcn_exp2f(mx * MXSCALE));
    }
    #undef STAGE
}

// ---------------------------------------------------------------------------
// Kernel 3: combine 8 partials per query row, write flow + conf
// ---------------------------------------------------------------------------
__global__ __launch_bounds__(256) void combine_kernel(const float4* __restrict__ part,
                                                      float* __restrict__ out)
{
    int tid = blockIdx.x * 256 + threadIdx.x;   // 0 .. B*HW-1 (grid sized exactly)
    int b = tid / HW, pos = tid % HW;
    float l = 0.f, ax = 0.f, ay = 0.f, mx = 0.f;
    #pragma unroll
    for (int s = 0; s < 8; ++s) {
        float4 v = part[(size_t)s * (BATCH * HW) + tid];   // coalesced
        l += v.x; ax += v.y; ay += v.z; mx = fmaxf(mx, v.w);
    }
    float inv = 1.0f / l;
    int x = pos % WIDTH, y = pos / WIDTH;
    out[(size_t)b * 2 * HW + pos]           = ax * inv - (float)x;
    out[(size_t)b * 2 * HW + HW + pos]      = ay * inv - (float)y;
    out[(size_t)BATCH * 2 * HW + (size_t)b * HW + pos] = mx * inv;
}

// ---------------------------------------------------------------------------
extern "C" void kernel_launch(void* const* d_in, const int* in_sizes, int n_in,
                              void* d_out, int out_size, void* d_ws, size_t ws_size,
                              hipStream_t stream)
{
    const float* fL = (const float*)d_in[0];
    const float* fR = (const float*)d_in[1];
    float* out = (float*)d_out;

    char* ws = (char*)d_ws;
    const size_t QH_BYTES = (size_t)BATCH * HW * CDIM * sizeof(_Float16);  // 4.72 MB
    _Float16* Qh  = (_Float16*)ws;
    _Float16* Kh  = (_Float16*)(ws + QH_BYTES);
    float4*   part = (float4*)(ws + 2 * QH_BYTES);                         // 2.36 MB

    norm_kernel<<<dim3((BATCH * HW) / 64, 2), 256, 0, stream>>>(fL, fR, Qh, Kh);
    attn_kernel<<<dim3(NWG), 512, 0, stream>>>(Qh, Kh, part);
    combine_kernel<<<dim3((BATCH * HW) / 256), 256, 0, stream>>>(part, out);
}

// Round 3
// 142.564 us; speedup vs baseline: 2.4463x; 2.4463x over previous
//
#include <hip/hip_runtime.h>
#include <stdint.h>

#define HW 9216
#define CDIM 128
#define WIDTH 96
#define BATCH 2
#define SPLITS 4            // 4 key-splits x 2 wk-waves = 8 partial streams
#define KSPLIT 2304         // keys per split
#define NTILE 36            // 2304 / 64 keys per LDS tile
#define QTILE 128           // q-rows per block
#define NQT (HW / QTILE)    // 72 q-tiles
#define NWG (NQT * SPLITS * BATCH)   // 576 blocks -> all co-resident

// Logits: w = dot * QSCALE, e = (e^w)^2 = exp(dot/(0.1*sqrt(128))).
// |dot|<=1 -> |w|<=0.442: packed Taylor-4 + square, rel err ~3e-4 (<< f16 noise).
#define QSCALE 0.44194173824159216f
// conf numerator: exp(2*mx) = exp2(mx * 2/ln2)
#define MXSCALE 2.8853900817779268f

typedef _Float16 half8 __attribute__((ext_vector_type(8)));
typedef float f32x16 __attribute__((ext_vector_type(16)));
typedef float float2v __attribute__((ext_vector_type(2)));

// ---------------------------------------------------------------------------
// Kernel 1: L2-normalize over C, write fp16 [B][HW][C] (unchanged).
// ---------------------------------------------------------------------------
__global__ __launch_bounds__(256) void norm_kernel(const float* __restrict__ fL,
                                                   const float* __restrict__ fR,
                                                   _Float16* __restrict__ Qh,
                                                   _Float16* __restrict__ Kh)
{
    __shared__ float ssred[4][64];
    __shared__ _Float16 ot[64 * 130];   // +2 halves pad -> bank advance 1/row

    const float* src = (blockIdx.y == 0) ? fL : fR;
    _Float16* dst    = (blockIdx.y == 0) ? Qh : Kh;
    const float outScale = (blockIdx.y == 0) ? QSCALE : 1.0f;

    const int t = threadIdx.x;
    const int pos_l = t & 63, cg = t >> 6;            // 4 channel groups of 32
    const int pos0 = blockIdx.x * 64;                  // 64 | HW so no straddle
    const int b = pos0 / HW, pos_in = pos0 % HW + pos_l;

    const float* p = src + (size_t)b * CDIM * HW + pos_in;

    float v[32];
    float ss = 0.f;
    #pragma unroll
    for (int j = 0; j < 32; ++j) {
        v[j] = p[(size_t)(cg * 32 + j) * HW];
        ss += v[j] * v[j];
    }
    ssred[cg][pos_l] = ss;
    __syncthreads();
    float tot = ssred[0][pos_l] + ssred[1][pos_l] + ssred[2][pos_l] + ssred[3][pos_l];
    float scale = outScale / fmaxf(sqrtf(tot), 1e-6f);

    #pragma unroll
    for (int j = 0; j < 32; ++j)
        ot[pos_l * 130 + cg * 32 + j] = (_Float16)(v[j] * scale);
    __syncthreads();

    uint4* og = (uint4*)(dst + (size_t)(b * HW + pos0 % HW + 0) * CDIM);
    #pragma unroll
    for (int i = 0; i < 4; ++i) {
        int idx = i * 256 + t;            // 0..1023 dwordx4 slots
        int row = idx >> 4, chunk = idx & 15;
        og[idx] = *(const uint4*)&ot[row * 130 + chunk * 8];
    }
}

// ---------------------------------------------------------------------------
// Kernel 2: fused correlation + softmax-accumulate, counted-vmcnt pipeline.
//   Block: 512 thr = 8 waves as 4(wq) x 2(wk) over 128q x 64k tiles.
//   LDS: 3 x 16 KB buffers, prefetch depth 2. Per tile:
//   sched_barrier(0); s_waitcnt vmcnt(2) (tile-t DMA landed, tile t+1 stays
//   IN FLIGHT -- never drained to 0); raw s_barrier; issue STAGE(t+2);
//   ds_read frags; 8 swapped 32x32x16 MFMA; poly-exp epilogue.
//   launch_bounds(512,4): VGPR cap 128 (state ~110) -- round 2's (512,6)
//   capped VGPR at 40 and spilled 650 MB/launch to scratch. Never again.
//   Loop rolled 11 x 3-phase + peeled 3-tile tail: compile-time buffer/phase
//   indices, ~4 KB I-cache instead of 26 KB fully unrolled.
//   XCD-chunked remap: 576 = 8 x 72 -> each XCD owns one (split,b): K-split
//   (576 KB) + Q slice (2.36 MB) L2-resident.
// ---------------------------------------------------------------------------
__global__ __launch_bounds__(512, 4) void attn_kernel(const _Float16* __restrict__ Qh,
                                                      const _Float16* __restrict__ Kh,
                                                      float4* __restrict__ part)
{
    __shared__ __align__(16) _Float16 Ks[3 * 64 * 128];   // 3 x 16 KB

    // bijective XCD swizzle (NWG % 8 == 0): xcd = wg & 7 gets chunk of 72
    const int wg0 = blockIdx.x;
    const int nid = (wg0 & 7) * (NWG / 8) + (wg0 >> 3);
    const int qt = nid % NQT;
    const int split = (nid / NQT) % SPLITS;
    const int b = nid / (NQT * SPLITS);

    const int t = threadIdx.x;
    const int lane = t & 63, wave = t >> 6;        // 8 waves
    const int wq = wave >> 1, wk = wave & 1;       // 4 (q) x 2 (k)
    const int lane31 = lane & 31, hi = lane >> 5;
    const int ln15 = lane & 15, qd = lane >> 4;

    const char* kp0 = (const char*)(Kh + (size_t)b * HW * CDIM) +
                      (size_t)(split * KSPLIT) * (CDIM * 2);

    // ---- Q fragments (B-operand): col = lane31 = q-row, k = hi*8+j ----
    half8 qf[8];
    {
        const char* qb = (const char*)(Qh +
            ((size_t)(b * HW + qt * QTILE + wq * 32 + lane31)) * CDIM);
        #pragma unroll
        for (int kc = 0; kc < 8; ++kc)
            qf[kc] = *(const half8*)(qb + kc * 32 + hi * 16);
    }

    // staging: wave stages rows [wave*8, wave*8+8) of the 64-row tile.
    // LDS dest linear (instr adds lane*16B); source 16B-chunk XOR-swizzled so
    // LDS[r][c] = K[r][c ^ (r&15)] -> conflict-free fragment reads.
    int voff[2];
    #pragma unroll
    for (int i = 0; i < 2; ++i) {
        int r = wave * 8 + i * 4 + qd;
        voff[i] = r * 256 + ((ln15 ^ (r & 15)) << 4);
    }

    // KB = byte address of the 16 KB tile to stage; BUF = LDS buffer 0..2
    #define STAGE(KB, BUF)                                                       \
        {                                                                        \
            const char* kb_ = (KB);                                              \
            _Float16* db_ = &Ks[(BUF) * 8192 + wave * (8 * 128)];                \
            _Pragma("unroll")                                                    \
            for (int i_ = 0; i_ < 2; ++i_)                                       \
                __builtin_amdgcn_global_load_lds(                                \
                    (const __attribute__((address_space(1))) uint32_t*)(kb_ + voff[i_]), \
                    (__attribute__((address_space(3))) uint32_t*)(db_ + i_ * (4 * 128)), \
                    16, 0, 0);                                                   \
        }

    // prologue: pin issue order qf -> STAGE(0) -> STAGE(1) so vmcnt counts
    // in the loop refer to the DMAs we think they do.
    __builtin_amdgcn_sched_barrier(0);
    STAGE(kp0, 0);
    __builtin_amdgcn_sched_barrier(0);
    STAGE(kp0 + 16384, 1);

    // K-frag (A-operand) LDS byte offsets: row = wk*32 + lane31, chunk
    // (kc*2+hi) un-swizzled via ^ln15 (row&15 == ln15).
    int rdoff[8];
    #pragma unroll
    for (int kc = 0; kc < 8; ++kc)
        rdoff[kc] = ((wk * 32 + lane31) << 8) + ((((kc << 1) | hi) ^ ln15) << 4);

    // period-3 coordinate tables:
    // key = split*2304 + kt*64 + wk*32 + crow + 4hi;
    // x = 32*((2kt+wk)%3) + crow + 4hi (never wraps: base<=64, off<=31)
    // y = split*24 + (2kt+wk)/3 + 2*(kt/3)
    float xb[3], yw[3];
    #pragma unroll
    for (int p = 0; p < 3; ++p) {
        xb[p] = (float)(32 * ((2 * p + wk) % 3));
        yw[p] = (float)(split * 24 + (2 * p + wk) / 3);
    }

    float2v E2[8];                       // per reg-pair e-sums (crow applied at end)
    #pragma unroll
    for (int p = 0; p < 8; ++p) E2[p] = (float2v)0.f;
    float2v mx2 = (float2v)(-1.0e30f);
    float2v axb2 = (float2v)0.f, ay2 = (float2v)0.f;

    const char* ksb = (const char*)&Ks[0];
    const float2v C4 = (float2v)(1.0f / 24.0f), C3 = (float2v)(1.0f / 6.0f),
                  C2 = (float2v)0.5f, C1 = (float2v)1.0f;

    // one 64-key tile at phase P (compile-time 0..2). DOSTAGE: prefetch
    // tile kbase+(P+2)*16384 into buf (P+2)%3. VM: literal vmcnt.
    #define TILE_BODY(P, DOSTAGE, VM)                                            \
        {                                                                        \
            __builtin_amdgcn_sched_barrier(0);                                   \
            asm volatile("s_waitcnt vmcnt(" #VM ")" ::: "memory");               \
            __builtin_amdgcn_s_barrier();                                        \
            __builtin_amdgcn_sched_barrier(0);                                   \
            if (DOSTAGE) STAGE(kbase + ((P) + 2) * 16384, ((P) + 2) % 3);        \
            f32x16 acc;                                                          \
            __builtin_amdgcn_s_setprio(1);                                       \
            _Pragma("unroll")                                                    \
            for (int kc = 0; kc < 8; ++kc) {                                     \
                half8 kf = *(const half8*)(ksb + (P) * 16384 + rdoff[kc]);       \
                acc = __builtin_amdgcn_mfma_f32_32x32x16_f16(                    \
                    kf, qf[kc], (kc == 0) ? (f32x16)0.f : acc, 0, 0, 0);         \
            }                                                                    \
            __builtin_amdgcn_s_setprio(0);                                       \
            float2v lt2;                                                         \
            _Pragma("unroll")                                                    \
            for (int p = 0; p < 8; ++p) {                                        \
                float2v w;                                                       \
                w.x = acc[2 * p];                                                \
                w.y = acc[2 * p + 1];                                            \
                mx2 = __builtin_elementwise_max(mx2, w);                         \
                float2v h = w * C4 + C3;                                         \
                h = h * w + C2;                                                  \
                h = h * w + C1;                                                  \
                h = h * w + C1;                                                  \
                float2v e = h * h;                                               \
                E2[p] += e;                                                      \
                lt2 = (p == 0) ? e : (lt2 + e);                                  \
            }                                                                    \
            axb2 += lt2 * (float2v)xb[P];                                        \
            ay2  += lt2 * (float2v)(yw[P] + yy);                                 \
        }

    const char* kbase = kp0;
    float yy = 0.f;
    for (int kt3 = 0; kt3 < 11; ++kt3) {       // tiles 0..32, all full-pipeline
        TILE_BODY(0, 1, 2)
        TILE_BODY(1, 1, 2)
        TILE_BODY(2, 1, 2)
        kbase += 3 * 16384;
        yy += 2.0f;
    }
    // peeled tail: tiles 33 (stages 35), 34, 35
    TILE_BODY(0, 1, 2)
    TILE_BODY(1, 0, 2)
    TILE_BODY(2, 0, 0)
    #undef TILE_BODY

    // ---- per-lane fold: apply compile-time crow weights once ----
    float l = 0.f, axc = 0.f;
    #pragma unroll
    for (int p = 0; p < 8; ++p) {
        const float c0 = (float)(((2 * p) & 3) + 8 * ((2 * p) >> 2)); // 0,2,8,...,26
        l   += E2[p].x + E2[p].y;
        axc += c0 * E2[p].x + (c0 + 1.0f) * E2[p].y;
    }
    float ax = axc + (float)(4 * hi) * l + axb2.x + axb2.y;
    float ay = ay2.x + ay2.y;
    float mx = fmaxf(mx2.x, mx2.y);

    // combine hi/lo key-halves (lanes l and l+32 share q = lane31)
    l  += __shfl_xor(l, 32, 64);
    ax += __shfl_xor(ax, 32, 64);
    ay += __shfl_xor(ay, 32, 64);
    mx  = fmaxf(mx, __shfl_xor(mx, 32, 64));

    if (hi == 0) {
        int row = qt * QTILE + wq * 32 + lane31;
        part[(size_t)(split * 2 + wk) * (BATCH * HW) + b * HW + row] =
            make_float4(l, ax, ay, __builtin_amdgcn_exp2f(mx * MXSCALE));
    }
    #undef STAGE
}

// ---------------------------------------------------------------------------
// Kernel 3: combine 8 partials per query row, write flow + conf
// ---------------------------------------------------------------------------
__global__ __launch_bounds__(256) void combine_kernel(const float4* __restrict__ part,
                                                      float* __restrict__ out)
{
    int tid = blockIdx.x * 256 + threadIdx.x;   // 0 .. B*HW-1 (grid sized exactly)
    int b = tid / HW, pos = tid % HW;
    float l = 0.f, ax = 0.f, ay = 0.f, mx = 0.f;
    #pragma unroll
    for (int s = 0; s < 8; ++s) {
        float4 v = part[(size_t)s * (BATCH * HW) + tid];   // coalesced
        l += v.x; ax += v.y; ay += v.z; mx = fmaxf(mx, v.w);
    }
    float inv = 1.0f / l;
    int x = pos % WIDTH, y = pos / WIDTH;
    out[(size_t)b * 2 * HW + pos]           = ax * inv - (float)x;
    out[(size_t)b * 2 * HW + HW + pos]      = ay * inv - (float)y;
    out[(size_t)BATCH * 2 * HW + (size_t)b * HW + pos] = mx * inv;
}

// ---------------------------------------------------------------------------
extern "C" void kernel_launch(void* const* d_in, const int* in_sizes, int n_in,
                              void* d_out, int out_size, void* d_ws, size_t ws_size,
                              hipStream_t stream)
{
    const float* fL = (const float*)d_in[0];
    const float* fR = (const float*)d_in[1];
    float* out = (float*)d_out;

    char* ws = (char*)d_ws;
    const size_t QH_BYTES = (size_t)BATCH * HW * CDIM * sizeof(_Float16);  // 4.72 MB
    _Float16* Qh  = (_Float16*)ws;
    _Float16* Kh  = (_Float16*)(ws + QH_BYTES);
    float4*   part = (float4*)(ws + 2 * QH_BYTES);                         // 2.36 MB

    norm_kernel<<<dim3((BATCH * HW) / 64, 2), 256, 0, stream>>>(fL, fR, Qh, Kh);
    attn_kernel<<<dim3(NWG), 512, 0, stream>>>(Qh, Kh, part);
    combine_kernel<<<dim3((BATCH * HW) / 256), 256, 0, stream>>>(part, out);
}

// Round 5
// 132.294 us; speedup vs baseline: 2.6362x; 1.0776x over previous
//
#include <hip/hip_runtime.h>
#include <stdint.h>

#define HW 9216
#define CDIM 128
#define WIDTH 96
#define BATCH 2
#define SPLITS 32           // 32 key-splits -> 32 partial streams
#define KSPLIT 288          // keys per split; LDS = 288*256B = 72 KB (2 blocks/CU)
#define NKG 9               // 288 / 32 keys per key-group
#define QTILE 256           // q-rows per block (4 waves x 64q, 2 qsets of 32)
#define NQT (HW / QTILE)    // 36 q-tiles
#define NWG (NQT * SPLITS * BATCH)   // 2304 blocks

// Logits: w = dot * QSCALE, e = (e^w)^2 = exp(dot/(0.1*sqrt(128))).
// |dot|<=1 -> |w|<=0.442: packed Taylor-4 + square, rel err ~3e-4 (<< f16 noise).
#define QSCALE 0.44194173824159216f
// conf numerator: exp(2*mx) = exp2(mx * 2/ln2)
#define MXSCALE 2.8853900817779268f

typedef _Float16 half8 __attribute__((ext_vector_type(8)));
typedef float f32x16 __attribute__((ext_vector_type(16)));
typedef float float2v __attribute__((ext_vector_type(2)));

// ---------------------------------------------------------------------------
// Kernel 1: L2-normalize over C, write fp16 [B][HW][C] (unchanged).
// ---------------------------------------------------------------------------
__global__ __launch_bounds__(256) void norm_kernel(const float* __restrict__ fL,
                                                   const float* __restrict__ fR,
                                                   _Float16* __restrict__ Qh,
                                                   _Float16* __restrict__ Kh)
{
    __shared__ float ssred[4][64];
    __shared__ _Float16 ot[64 * 130];   // +2 halves pad -> bank advance 1/row

    const float* src = (blockIdx.y == 0) ? fL : fR;
    _Float16* dst    = (blockIdx.y == 0) ? Qh : Kh;
    const float outScale = (blockIdx.y == 0) ? QSCALE : 1.0f;

    const int t = threadIdx.x;
    const int pos_l = t & 63, cg = t >> 6;            // 4 channel groups of 32
    const int pos0 = blockIdx.x * 64;                  // 64 | HW so no straddle
    const int b = pos0 / HW, pos_in = pos0 % HW + pos_l;

    const float* p = src + (size_t)b * CDIM * HW + pos_in;

    float v[32];
    float ss = 0.f;
    #pragma unroll
    for (int j = 0; j < 32; ++j) {
        v[j] = p[(size_t)(cg * 32 + j) * HW];
        ss += v[j] * v[j];
    }
    ssred[cg][pos_l] = ss;
    __syncthreads();
    float tot = ssred[0][pos_l] + ssred[1][pos_l] + ssred[2][pos_l] + ssred[3][pos_l];
    float scale = outScale / fmaxf(sqrtf(tot), 1e-6f);

    #pragma unroll
    for (int j = 0; j < 32; ++j)
        ot[pos_l * 130 + cg * 32 + j] = (_Float16)(v[j] * scale);
    __syncthreads();

    uint4* og = (uint4*)(dst + (size_t)(b * HW + pos0 % HW + 0) * CDIM);
    #pragma unroll
    for (int i = 0; i < 4; ++i) {
        int idx = i * 256 + t;            // 0..1023 dwordx4 slots
        int row = idx >> 4, chunk = idx & 15;
        og[idx] = *(const uint4*)&ot[row * 130 + chunk * 8];
    }
}

// ---------------------------------------------------------------------------
// Kernel 2: fused correlation + softmax-accumulate — PERSISTENT-K, barrier-free.
//   Rounds 0/1/3 (three different barrier/prefetch schedules) all ran the
//   same 165,888 per-wave 8-MFMA quanta at ~1120 cy each (~300 cy of issue
//   work) -> limiter is per-wave chain + per-tile barrier lockstep, not
//   staging. Fix: stage the block's ENTIRE 288-key split in LDS once
//   (72 KB), ONE barrier, then waves free-run 9 independent key-groups with
//   NO further sync. Each wave owns 64 q (2 qsets of 32): each kf LDS read
//   feeds 2 MFMAs (LDS traffic halves), the 2 acc chains interleave on the
//   matrix pipe, and kg t's epilogue overlaps kg t+1's ds_reads/MFMAs.
//   Block: 256 thr = 4 waves x 64q over 256q x 288k. 2 blocks/CU.
//   launch_bounds(256,2): VGPR cap 256 (state ~200) — NO SPILL (verify:
//   WRITE_SIZE must stay ~12-16 MB; round 2's spill signature was 650 MB).
//   XCD-chunked remap: 2304 = 8 x 288 -> each XCD owns 8 (split,b) pairs:
//   K-chunks ~590 KB + Q slices L2-resident.
// ---------------------------------------------------------------------------
__global__ __launch_bounds__(256, 2) void attn_kernel(const _Float16* __restrict__ Qh,
                                                      const _Float16* __restrict__ Kh,
                                                      float4* __restrict__ part)
{
    __shared__ __align__(16) _Float16 Ks[KSPLIT * 128];   // 72 KB, staged once

    // bijective XCD swizzle (NWG % 8 == 0): xcd = wg & 7 gets chunk of 288
    const int wg0 = blockIdx.x;
    const int nid = (wg0 & 7) * (NWG / 8) + (wg0 >> 3);
    const int qt = nid % NQT;
    const int sb = nid / NQT;            // 0..63, consecutive within an XCD
    const int split = sb & 31;
    const int b = sb >> 5;

    const int t = threadIdx.x;
    const int lane = t & 63, wave = t >> 6;        // 4 waves
    const int lane31 = lane & 31, hi = lane >> 5;
    const int ln15 = lane & 15, qd = lane >> 4;

    const char* kp0 = (const char*)(Kh + (size_t)b * HW * CDIM) +
                      (size_t)(split * KSPLIT) * (CDIM * 2);

    // ---- stage the whole K-split: wave stages rows [wave*72, wave*72+72) ----
    // 18 DMAs x (4 rows x 256B). LDS dest linear (instr adds lane*16B);
    // source 16B-chunk XOR-swizzled: LDS[r][c] = K[r][c ^ (r&15)] ->
    // conflict-free fragment reads. (r&15) has period 4 in the DMA index i,
    // so 4 base voffsets + i*1024 reconstruct r*256 + swz for all 18.
    {
        int voff4[4];
        #pragma unroll
        for (int i = 0; i < 4; ++i) {
            int r = wave * 72 + i * 4 + qd;
            voff4[i] = r * 256 + ((ln15 ^ (r & 15)) << 4) - i * 1024;
        }
        _Float16* db = &Ks[wave * (72 * 128)];
        #pragma unroll
        for (int i = 0; i < 18; ++i)
            __builtin_amdgcn_global_load_lds(
                (const __attribute__((address_space(1))) uint32_t*)(kp0 + voff4[i & 3] + i * 1024),
                (__attribute__((address_space(3))) uint32_t*)(db + i * 512),
                16, 0, 0);
    }

    // ---- Q fragments, 2 qsets (B-operand): col = lane31 = q-row, k = hi*8+j ----
    half8 qf[2][8];
    {
        #pragma unroll
        for (int s = 0; s < 2; ++s) {
            const char* qb = (const char*)(Qh +
                ((size_t)(b * HW + qt * QTILE + wave * 64 + s * 32 + lane31)) * CDIM);
            #pragma unroll
            for (int kc = 0; kc < 8; ++kc)
                qf[s][kc] = *(const half8*)(qb + kc * 32 + hi * 16);
        }
    }

    // K-frag (A-operand) LDS byte offsets for kg=0: row = lane31, chunk
    // (kc*2+hi) un-swizzled via ^ln15 (row&15 == ln15). kg adds kg*8192.
    int rdoff[8];
    #pragma unroll
    for (int kc = 0; kc < 8; ++kc)
        rdoff[kc] = (lane31 << 8) + ((((kc << 1) | hi) ^ ln15) << 4);

    // coordinates: key = split*288 + kg*32 + crow + 4hi; 288 % 96 == 0 ->
    // x = 32*(kg%3) + crow + 4hi (never wraps), y = split*3 + kg/3.
    const float ysp = (float)(split * 3);

    // per-qset state
    float2v E2[2][8];
    #pragma unroll
    for (int s = 0; s < 2; ++s)
        #pragma unroll
        for (int p = 0; p < 8; ++p) E2[s][p] = (float2v)0.f;
    float2v mx2[2], axb2[2], ay2[2];
    #pragma unroll
    for (int s = 0; s < 2; ++s) {
        mx2[s] = (float2v)(-1.0e30f);
        axb2[s] = (float2v)0.f;
        ay2[s] = (float2v)0.f;
    }

    const char* ksb = (const char*)&Ks[0];
    const float2v C4 = (float2v)(1.0f / 24.0f), C3 = (float2v)(1.0f / 6.0f),
                  C2 = (float2v)0.5f, C1 = (float2v)1.0f;

    __syncthreads();   // K fully staged (single vmcnt(0) drain of the run)

    // ---- free-running main loop: 9 independent key-groups, no sync ----
    #pragma unroll
    for (int kg = 0; kg < NKG; ++kg) {
        f32x16 acc[2];
        #pragma unroll
        for (int kc = 0; kc < 8; ++kc) {
            half8 kf = *(const half8*)(ksb + kg * 8192 + rdoff[kc]);
            #pragma unroll
            for (int s = 0; s < 2; ++s)
                acc[s] = __builtin_amdgcn_mfma_f32_32x32x16_f16(
                    kf, qf[s][kc], (kc == 0) ? (f32x16)0.f : acc[s], 0, 0, 0);
        }

        const float xb = (float)(32 * (kg % 3));
        const float yk = ysp + (float)(kg / 3);
        #pragma unroll
        for (int s = 0; s < 2; ++s) {
            float2v lt2;
            #pragma unroll
            for (int p = 0; p < 8; ++p) {
                float2v w;
                w.x = acc[s][2 * p];
                w.y = acc[s][2 * p + 1];
                mx2[s] = __builtin_elementwise_max(mx2[s], w);
                float2v h = w * C4 + C3;          // e^w, Taylor-4 on |w|<=0.442
                h = h * w + C2;
                h = h * w + C1;
                h = h * w + C1;
                float2v e = h * h;                // square back to full range
                E2[s][p] += e;
                lt2 = (p == 0) ? e : (lt2 + e);
            }
            axb2[s] += lt2 * (float2v)xb;
            ay2[s]  += lt2 * (float2v)yk;
        }
    }

    // ---- per-qset fold + hi/lo combine + store ----
    #pragma unroll
    for (int s = 0; s < 2; ++s) {
        float l = 0.f, axc = 0.f;
        #pragma unroll
        for (int p = 0; p < 8; ++p) {
            const float c0 = (float)(((2 * p) & 3) + 8 * ((2 * p) >> 2)); // 0,2,8,...,26
            l   += E2[s][p].x + E2[s][p].y;
            axc += c0 * E2[s][p].x + (c0 + 1.0f) * E2[s][p].y;
        }
        float ax = axc + (float)(4 * hi) * l + axb2[s].x + axb2[s].y;
        float ay = ay2[s].x + ay2[s].y;
        float mx = fmaxf(mx2[s].x, mx2[s].y);

        l  += __shfl_xor(l, 32, 64);
        ax += __shfl_xor(ax, 32, 64);
        ay += __shfl_xor(ay, 32, 64);
        mx  = fmaxf(mx, __shfl_xor(mx, 32, 64));

        if (hi == 0) {
            int row = qt * QTILE + wave * 64 + s * 32 + lane31;
            part[(size_t)split * (BATCH * HW) + b * HW + row] =
                make_float4(l, ax, ay, __builtin_amdgcn_exp2f(mx * MXSCALE));
        }
    }
}

// ---------------------------------------------------------------------------
// Kernel 3: combine 32 partials per query row, write flow + conf
// ---------------------------------------------------------------------------
__global__ __launch_bounds__(256) void combine_kernel(const float4* __restrict__ part,
                                                      float* __restrict__ out)
{
    int tid = blockIdx.x * 256 + threadIdx.x;   // 0 .. B*HW-1 (grid sized exactly)
    int b = tid / HW, pos = tid % HW;
    float l = 0.f, ax = 0.f, ay = 0.f, mx = 0.f;
    #pragma unroll
    for (int s = 0; s < SPLITS; ++s) {
        float4 v = part[(size_t)s * (BATCH * HW) + tid];   // coalesced
        l += v.x; ax += v.y; ay += v.z; mx = fmaxf(mx, v.w);
    }
    float inv = 1.0f / l;
    int x = pos % WIDTH, y = pos / WIDTH;
    out[(size_t)b * 2 * HW + pos]           = ax * inv - (float)x;
    out[(size_t)b * 2 * HW + HW + pos]      = ay * inv - (float)y;
    out[(size_t)BATCH * 2 * HW + (size_t)b * HW + pos] = mx * inv;
}

// ---------------------------------------------------------------------------
extern "C" void kernel_launch(void* const* d_in, const int* in_sizes, int n_in,
                              void* d_out, int out_size, void* d_ws, size_t ws_size,
                              hipStream_t stream)
{
    const float* fL = (const float*)d_in[0];
    const float* fR = (const float*)d_in[1];
    float* out = (float*)d_out;

    char* ws = (char*)d_ws;
    const size_t QH_BYTES = (size_t)BATCH * HW * CDIM * sizeof(_Float16);  // 4.72 MB
    _Float16* Qh  = (_Float16*)ws;
    _Float16* Kh  = (_Float16*)(ws + QH_BYTES);
    float4*   part = (float4*)(ws + 2 * QH_BYTES);                         // 9.44 MB

    norm_kernel<<<dim3((BATCH * HW) / 64, 2), 256, 0, stream>>>(fL, fR, Qh, Kh);
    attn_kernel<<<dim3(NWG), 256, 0, stream>>>(Qh, Kh, part);
    combine_kernel<<<dim3((BATCH * HW) / 256), 256, 0, stream>>>(part, out);
}